// Round 5
// baseline (766.226 us; speedup 1.0000x reference)
//
#include <hip/hip_runtime.h>
#include <hip/hip_bf16.h>

// LinkPredictorGAT: out[e] = relu(concat(z[src[e]], z[dst[e]]) @ W1 + b1) @ W2 + b2
// R4: whole B^T (128 KB) staged into LDS ONCE per block; persistent 512-thread
// blocks grid-stride over edge tiles with a BARRIER-FREE K-loop.
// R2 showed barriers correlate stalls (Mfma 20%); R3 showed B-from-global thrashes
// L1 (Mfma 13.7%). This keeps LDS bandwidth AND decoupled waves.

typedef __attribute__((ext_vector_type(4))) float floatx4;
typedef __attribute__((ext_vector_type(8))) short short8;

__device__ __forceinline__ unsigned short bf16rne(float x) {
    unsigned int u = __float_as_uint(x);
    u += 0x7fffu + ((u >> 16) & 1u);
    return (unsigned short)(u >> 16);
}

// ---- convert z (fp32 -> bf16), float4 per thread ----
__global__ void cvt_z(const float* __restrict__ z, unsigned short* __restrict__ zb, int n4) {
    int i = blockIdx.x * blockDim.x + threadIdx.x;
    if (i < n4) {
        float4 f = ((const float4*)z)[i];
        ushort4 u;
        u.x = bf16rne(f.x); u.y = bf16rne(f.y);
        u.z = bf16rne(f.z); u.w = bf16rne(f.w);
        ((ushort4*)zb)[i] = u;
    }
}

// ---- convert W1 [512][128] fp32 -> BT [128][512] bf16 (transposed), coalesced stores ----
__global__ void cvt_w1(const float* __restrict__ W1, unsigned short* __restrict__ BT) {
    int g = blockIdx.x * blockDim.x + threadIdx.x;   // 0..65535
    int n = g >> 9, k = g & 511;                     // consecutive threads -> consecutive k
    BT[g] = bf16rne(W1[k * 128 + n]);                // BT[n][k] = W1[k][n]
}

// ---- fused gather + GEMM(512x128) + bias + relu + GEMV(W2) ----
// 512 threads = 8 waves; wave tile 64 edges x 128 cols (mf=4, nf=8).
// LDS: full B^T in slabs [ks][n][32+2pad]: 16*128*34*2 = 139,264 B -> 1 block/CU.
// Fragment read bank = (16nf + 17*l15 + 4*quad) mod 32 -> exact 2-way (free, m136).
#define KS_SLAB 8704   // 128*34*2 bytes per ks slab
#define ROW_B   68     // 34 shorts * 2 bytes

template <bool ABF16>
__global__ __launch_bounds__(512, 2)
void fused_mlp(const float* __restrict__ zf, const unsigned short* __restrict__ zb,
               const int* __restrict__ eli, int E, int nnodes,
               const unsigned short* __restrict__ BT,
               const float* __restrict__ b1, const float* __restrict__ W2,
               const float* __restrict__ b2, float* __restrict__ out, int ntiles)
{
    __shared__ unsigned short btile[16 * 128 * 34];   // [ks][n][34]

    const int t = threadIdx.x;
    const int wid = t >> 6;        // 0..7
    const int lane = t & 63;
    const int l15 = lane & 15;
    const int quad = lane >> 4;

    // ---- one-time stage of full B^T into LDS (then barrier-free forever) ----
    {
        const int row = t >> 2;                    // n: 0..127
        const int kbase = (t & 3) * 128;           // 4 threads cover k=0..511
#pragma unroll
        for (int j8 = 0; j8 < 16; ++j8) {
            int k = kbase + j8 * 8;
            short8 v = *(const short8*)(BT + row * 512 + k);
            int ks = k >> 5, kc = k & 31;
            *(short8*)((char*)btile + ks * KS_SLAB + row * ROW_B + kc * 2) = v;
        }
    }
    __syncthreads();   // the ONLY barrier

    // epilogue constants: this lane's 8 columns
    float b1v[8], w2v[8];
#pragma unroll
    for (int nf = 0; nf < 8; ++nf) {
        int c = nf * 16 + l15;
        b1v[nf] = b1[c];
        w2v[nf] = W2[c];
    }
    const float b2s = b2[0];

    const char* zbb = (const char*)(ABF16 ? (const void*)zb : (const void*)zf);
    // lane-invariant part of B fragment address
    const char* bbase = (const char*)btile + l15 * ROW_B + quad * 16;

    for (int tile = blockIdx.x; tile < ntiles; tile += gridDim.x) {
        const int m0 = tile * 512 + wid * 64;      // this wave's first edge

        unsigned offs[4], offd[4];
#pragma unroll
        for (int mf = 0; mf < 4; ++mf) {
            int e = m0 + mf * 16 + l15;
            e = e < E ? e : E - 1;                 // clamp tail (stores masked later)
            int s = eli[e];
            int d = eli[E + e];
            s = s < 0 ? 0 : (s >= nnodes ? nnodes - 1 : s);
            d = d < 0 ? 0 : (d >= nnodes ? nnodes - 1 : d);
            offs[mf] = (unsigned)s * 512u;         // bf16 row bytes (fp32 path scales x2)
            offd[mf] = (unsigned)d * 512u;
        }

        floatx4 acc[4][8];
#pragma unroll
        for (int mf = 0; mf < 4; ++mf)
#pragma unroll
            for (int nf = 0; nf < 8; ++nf)
                acc[mf][nf] = (floatx4){0.f, 0.f, 0.f, 0.f};

        auto load_a = [&](int ks, short8* dst) {
            const unsigned* off = (ks < 8) ? offs : offd;
            if constexpr (ABF16) {
                const int cbytes = (ks & 7) * 64 + quad * 16;
#pragma unroll
                for (int mf = 0; mf < 4; ++mf)
                    dst[mf] = *(const short8*)(zbb + (size_t)off[mf] + cbytes);
            } else {
                const int cbytes = (ks & 7) * 128 + quad * 32;
#pragma unroll
                for (int mf = 0; mf < 4; ++mf) {
                    const float* pf = (const float*)(zbb + (size_t)off[mf] * 2 + cbytes);
                    float4 f0 = *(const float4*)pf;
                    float4 f1 = *(const float4*)(pf + 4);
                    short8 av;
                    av[0] = (short)bf16rne(f0.x); av[1] = (short)bf16rne(f0.y);
                    av[2] = (short)bf16rne(f0.z); av[3] = (short)bf16rne(f0.w);
                    av[4] = (short)bf16rne(f1.x); av[5] = (short)bf16rne(f1.y);
                    av[6] = (short)bf16rne(f1.z); av[7] = (short)bf16rne(f1.w);
                    dst[mf] = av;
                }
            }
        };

        short8 a_cur[4], a_nxt[4];
        load_a(0, a_cur);

#pragma unroll
        for (int ks = 0; ks < 16; ++ks) {
            if (ks + 1 < 16) load_a(ks + 1, a_nxt);   // depth-1 prefetch, survives (no barriers)

            const char* bks = bbase + ks * KS_SLAB;
            short8 bfr[8];
#pragma unroll
            for (int nf = 0; nf < 8; ++nf)
                bfr[nf] = *(const short8*)(bks + nf * 16 * ROW_B);

#pragma unroll
            for (int nf = 0; nf < 8; ++nf)
#pragma unroll
                for (int mf = 0; mf < 4; ++mf)
                    acc[mf][nf] = __builtin_amdgcn_mfma_f32_16x16x32_bf16(
                        a_cur[mf], bfr[nf], acc[mf][nf], 0, 0, 0);

#pragma unroll
            for (int mf = 0; mf < 4; ++mf) a_cur[mf] = a_nxt[mf];
        }

        // epilogue: h = relu(acc + b1); s = h . W2; reduce 128 cols
        // C/D layout: col = lane&15 (+16*nf), row = quad*4 + r (+16*mf)
#pragma unroll
        for (int mf = 0; mf < 4; ++mf) {
#pragma unroll
            for (int r = 0; r < 4; ++r) {
                float s = 0.f;
#pragma unroll
                for (int nf = 0; nf < 8; ++nf) {
                    float v = acc[mf][nf][r] + b1v[nf];
                    v = v > 0.f ? v : 0.f;
                    s = fmaf(v, w2v[nf], s);
                }
                s += __shfl_xor(s, 1);
                s += __shfl_xor(s, 2);
                s += __shfl_xor(s, 4);
                s += __shfl_xor(s, 8);
                if (l15 == 0) {
                    int e = m0 + mf * 16 + quad * 4 + r;
                    if (e < E) out[e] = s + b2s;
                }
            }
        }
    }
}

// ---- emergency fallback (tiny ws): one block per edge, fp32 vector ----
__global__ void naive_edge(const float* __restrict__ z, const int* __restrict__ eli,
                           int E, int nnodes,
                           const float* __restrict__ W1, const float* __restrict__ b1,
                           const float* __restrict__ W2, const float* __restrict__ b2,
                           float* __restrict__ out)
{
    __shared__ float red[2];
    int e = blockIdx.x;
    int j = threadIdx.x;
    int s = eli[e], d = eli[E + e];
    s = s < 0 ? 0 : (s >= nnodes ? nnodes - 1 : s);
    d = d < 0 ? 0 : (d >= nnodes ? nnodes - 1 : d);
    const float* zs = z + (long long)s * 256;
    const float* zd = z + (long long)d * 256;
    float h = b1[j];
    for (int i = 0; i < 256; ++i) h = fmaf(zs[i], W1[i * 128 + j], h);
    for (int i = 0; i < 256; ++i) h = fmaf(zd[i], W1[(256 + i) * 128 + j], h);
    h = h > 0.f ? h : 0.f;
    float v = h * W2[j];
    v += __shfl_xor(v, 1);  v += __shfl_xor(v, 2);  v += __shfl_xor(v, 4);
    v += __shfl_xor(v, 8);  v += __shfl_xor(v, 16); v += __shfl_xor(v, 32);
    if ((threadIdx.x & 63) == 0) red[threadIdx.x >> 6] = v;
    __syncthreads();
    if (threadIdx.x == 0) out[e] = red[0] + red[1] + b2[0];
}

extern "C" void kernel_launch(void* const* d_in, const int* in_sizes, int n_in,
                              void* d_out, int out_size, void* d_ws, size_t ws_size,
                              hipStream_t stream) {
    const float* z   = (const float*)d_in[0];
    const int*   eli = (const int*)d_in[1];      // int64 in reference -> int32 on device
    const float* W1  = (const float*)d_in[2];
    const float* b1  = (const float*)d_in[3];
    const float* W2  = (const float*)d_in[4];
    const float* b2  = (const float*)d_in[5];
    float*       out = (float*)d_out;

    const int E      = in_sizes[1] / 2;
    const int nnodes = in_sizes[0] / 256;

    const size_t ZB  = (size_t)nnodes * 256 * 2;   // z in bf16
    const size_t BTB = (size_t)512 * 128 * 2;      // W1^T in bf16

    const int ntiles = (E + 511) / 512;
    const int grid_main = ntiles < 256 ? ntiles : 256;   // persistent, 1 block/CU

    if (ws_size >= ZB + BTB) {
        unsigned short* zb = (unsigned short*)d_ws;
        unsigned short* BT = (unsigned short*)((char*)d_ws + ZB);
        int n4 = nnodes * 64;
        cvt_z<<<(n4 + 255) / 256, 256, 0, stream>>>(z, zb, n4);
        cvt_w1<<<256, 256, 0, stream>>>(W1, BT);
        fused_mlp<true><<<grid_main, 512, 0, stream>>>(nullptr, zb, eli, E, nnodes, BT, b1, W2, b2, out, ntiles);
    } else if (ws_size >= BTB) {
        unsigned short* BT = (unsigned short*)d_ws;
        cvt_w1<<<256, 256, 0, stream>>>(W1, BT);
        fused_mlp<false><<<grid_main, 512, 0, stream>>>(z, nullptr, eli, E, nnodes, BT, b1, W2, b2, out, ntiles);
    } else {
        naive_edge<<<E, 128, 0, stream>>>(z, eli, E, nnodes, W1, b1, W2, b2, out);
    }
}

// Round 6
// 362.658 us; speedup vs baseline: 2.1128x; 2.1128x over previous
//
#include <hip/hip_runtime.h>
#include <hip/hip_bf16.h>

// LinkPredictorGAT: out[e] = relu(concat(z[src[e]], z[dst[e]]) @ W1 + b1) @ W2 + b2
// R5 = R2 skeleton (best: 262us) + cross-chunk depth-2 A prefetch + double-buffered
// LDS B (1 barrier/chunk) + register diet (epilogue consts loaded late).
// R2 post-mortem: A-gather latency was exposed per chunk (issued+consumed between
// barriers). R4 post-mortem: exceeding 256 unified regs spills 16 B/thr/kstep
// (WRITE_SIZE 258 MB). Both addressed here.

typedef __attribute__((ext_vector_type(4))) float floatx4;
typedef __attribute__((ext_vector_type(8))) short short8;

__device__ __forceinline__ unsigned short bf16rne(float x) {
    unsigned int u = __float_as_uint(x);
    u += 0x7fffu + ((u >> 16) & 1u);
    return (unsigned short)(u >> 16);
}

// ---- convert z (fp32 -> bf16), float4 per thread ----
__global__ void cvt_z(const float* __restrict__ z, unsigned short* __restrict__ zb, int n4) {
    int i = blockIdx.x * blockDim.x + threadIdx.x;
    if (i < n4) {
        float4 f = ((const float4*)z)[i];
        ushort4 u;
        u.x = bf16rne(f.x); u.y = bf16rne(f.y);
        u.z = bf16rne(f.z); u.w = bf16rne(f.w);
        ((ushort4*)zb)[i] = u;
    }
}

// ---- convert W1 [512][128] fp32 -> BT [128][512] bf16 (transposed), coalesced stores ----
__global__ void cvt_w1(const float* __restrict__ W1, unsigned short* __restrict__ BT) {
    int g = blockIdx.x * blockDim.x + threadIdx.x;   // 0..65535
    int n = g >> 9, k = g & 511;                     // consecutive threads -> consecutive k
    BT[g] = bf16rne(W1[k * 128 + n]);                // BT[n][k] = W1[k][n]
}

// ---- fused gather + GEMM(512x128) + bias + relu + GEMV(W2) ----
// 256 threads = 4 waves; wave tile 64 edges x 128 cols (mf=4, nf=8); 256 edges/block.
// LDS: double-buffered B chunk [buf][ks2][n=128][32+2pad] shorts = 34,816 B.
// Row stride 34 shorts = 17 dwords (odd) -> exact 2-way bank aliasing (free, m136).
template <bool ABF16>
__global__ __launch_bounds__(256, 2)
void fused_mlp(const float* __restrict__ zf, const unsigned short* __restrict__ zb,
               const int* __restrict__ eli, int E, int nnodes,
               const unsigned short* __restrict__ BT,
               const float* __restrict__ b1, const float* __restrict__ W2,
               const float* __restrict__ b2, float* __restrict__ out)
{
    __shared__ unsigned short btile[2][2][128][34];

    const int t = threadIdx.x;
    const int wid = t >> 6;
    const int lane = t & 63;
    const int l15 = lane & 15;
    const int quad = lane >> 4;
    const int m0 = blockIdx.x * 256 + wid * 64;

    // gather byte offsets for this lane's 4 src / 4 dst rows
    unsigned offs[4], offd[4];
#pragma unroll
    for (int mf = 0; mf < 4; ++mf) {
        int e = m0 + mf * 16 + l15;
        e = e < E ? e : E - 1;                 // clamp tail (stores masked later)
        int s = eli[e];
        int d = eli[E + e];
        s = s < 0 ? 0 : (s >= nnodes ? nnodes - 1 : s);
        d = d < 0 ? 0 : (d >= nnodes ? nnodes - 1 : d);
        offs[mf] = (unsigned)s * 512u;         // bf16 row = 512 B (fp32 path scales x2)
        offd[mf] = (unsigned)d * 512u;
    }
    const char* zbb = (const char*)(ABF16 ? (const void*)zb : (const void*)zf);

    floatx4 acc[4][8];
#pragma unroll
    for (int mf = 0; mf < 4; ++mf)
#pragma unroll
        for (int nf = 0; nf < 8; ++nf)
            acc[mf][nf] = (floatx4){0.f, 0.f, 0.f, 0.f};

    // ---- staging helpers: 16 KB B chunk, 4 x 16 B per thread, fully coalesced ----
    auto stage_ld = [&](int kc, short8* s) {
#pragma unroll
        for (int i = 0; i < 4; ++i) {
            int p = t + i * 256;               // 0..1023 pieces of 8 shorts
            s[i] = *(const short8*)(BT + (p >> 3) * 512 + kc * 64 + (p & 7) * 8);
        }
    };
    auto stage_st = [&](int buf, short8* s) {
#pragma unroll
        for (int i = 0; i < 4; ++i) {
            int p = t + i * 256;
            int n = p >> 3, c = (p & 7) * 8;   // c in [0,64)
            *(short8*)&btile[buf][c >> 5][n][c & 31] = s[i];
        }
    };

    // ---- A loader: ks in [0,16); src half (ks<8) or dst half ----
    auto load_a = [&](int ks, short8* dst) {
        const unsigned* off = (ks < 8) ? offs : offd;
        if constexpr (ABF16) {
            const int cbytes = (ks & 7) * 64 + quad * 16;
#pragma unroll
            for (int mf = 0; mf < 4; ++mf)
                dst[mf] = *(const short8*)(zbb + (size_t)off[mf] + cbytes);
        } else {
            const int cbytes = (ks & 7) * 128 + quad * 32;
#pragma unroll
            for (int mf = 0; mf < 4; ++mf) {
                const float* pf = (const float*)(zbb + (size_t)off[mf] * 2 + cbytes);
                float4 f0 = *(const float4*)pf;
                float4 f1 = *(const float4*)(pf + 4);
                short8 av;
                av[0] = (short)bf16rne(f0.x); av[1] = (short)bf16rne(f0.y);
                av[2] = (short)bf16rne(f0.z); av[3] = (short)bf16rne(f0.w);
                av[4] = (short)bf16rne(f1.x); av[5] = (short)bf16rne(f1.y);
                av[6] = (short)bf16rne(f1.z); av[7] = (short)bf16rne(f1.w);
                dst[mf] = av;
            }
        }
    };

    // ---- prologue: stage chunk 0, prefetch A for ks=0,1 ----
    short8 A[3][4];                            // depth-2 rolling A prefetch
    {
        short8 s0[4];
        stage_ld(0, s0);
        load_a(0, A[0]);
        load_a(1, A[1]);
        stage_st(0, s0);
    }
    __syncthreads();                           // buf0 ready

    // ---- K-loop: 8 chunks x 2 MFMA steps; ONE barrier per chunk ----
#pragma unroll
    for (int kc = 0; kc < 8; ++kc) {
        short8 sreg[4];
        if (kc < 7) stage_ld(kc + 1, sreg);    // global loads in flight across compute

#pragma unroll
        for (int ks2 = 0; ks2 < 2; ++ks2) {
            const int ks = kc * 2 + ks2;
            if (ks + 2 < 16) load_a(ks + 2, A[(ks + 2) % 3]);   // depth-2 A prefetch

            short8 bfr[8];
#pragma unroll
            for (int nf = 0; nf < 8; ++nf)
                bfr[nf] = *(const short8*)&btile[kc & 1][ks2][nf * 16 + l15][quad * 8];

            const short8* ac = A[ks % 3];
#pragma unroll
            for (int nf = 0; nf < 8; ++nf)
#pragma unroll
                for (int mf = 0; mf < 4; ++mf)
                    acc[mf][nf] = __builtin_amdgcn_mfma_f32_16x16x32_bf16(
                        ac[mf], bfr[nf], acc[mf][nf], 0, 0, 0);
        }

        if (kc < 7) {
            stage_st((kc + 1) & 1, sreg);      // waits vmcnt here (overlapped)
            __syncthreads();                   // publish buf (kc+1)&1; protects reuse
        }
    }

    // ---- epilogue (consts loaded LATE to keep main-loop registers lean) ----
    const float b2s = b2[0];
    float b1v[8], w2v[8];
#pragma unroll
    for (int nf = 0; nf < 8; ++nf) {
        int c = nf * 16 + l15;
        b1v[nf] = b1[c];
        w2v[nf] = W2[c];
    }
    // C/D layout: col = lane&15 (+16*nf), row = quad*4 + r (+16*mf)
#pragma unroll
    for (int mf = 0; mf < 4; ++mf) {
#pragma unroll
        for (int r = 0; r < 4; ++r) {
            float s = 0.f;
#pragma unroll
            for (int nf = 0; nf < 8; ++nf) {
                float v = acc[mf][nf][r] + b1v[nf];
                v = v > 0.f ? v : 0.f;
                s = fmaf(v, w2v[nf], s);
            }
            s += __shfl_xor(s, 1);
            s += __shfl_xor(s, 2);
            s += __shfl_xor(s, 4);
            s += __shfl_xor(s, 8);
            if (l15 == 0) {
                int e = m0 + mf * 16 + quad * 4 + r;
                if (e < E) out[e] = s + b2s;
            }
        }
    }
}

// ---- emergency fallback (tiny ws): one block per edge, fp32 vector ----
__global__ void naive_edge(const float* __restrict__ z, const int* __restrict__ eli,
                           int E, int nnodes,
                           const float* __restrict__ W1, const float* __restrict__ b1,
                           const float* __restrict__ W2, const float* __restrict__ b2,
                           float* __restrict__ out)
{
    __shared__ float red[2];
    int e = blockIdx.x;
    int j = threadIdx.x;
    int s = eli[e], d = eli[E + e];
    s = s < 0 ? 0 : (s >= nnodes ? nnodes - 1 : s);
    d = d < 0 ? 0 : (d >= nnodes ? nnodes - 1 : d);
    const float* zs = z + (long long)s * 256;
    const float* zd = z + (long long)d * 256;
    float h = b1[j];
    for (int i = 0; i < 256; ++i) h = fmaf(zs[i], W1[i * 128 + j], h);
    for (int i = 0; i < 256; ++i) h = fmaf(zd[i], W1[(256 + i) * 128 + j], h);
    h = h > 0.f ? h : 0.f;
    float v = h * W2[j];
    v += __shfl_xor(v, 1);  v += __shfl_xor(v, 2);  v += __shfl_xor(v, 4);
    v += __shfl_xor(v, 8);  v += __shfl_xor(v, 16); v += __shfl_xor(v, 32);
    if ((threadIdx.x & 63) == 0) red[threadIdx.x >> 6] = v;
    __syncthreads();
    if (threadIdx.x == 0) out[e] = red[0] + red[1] + b2[0];
}

extern "C" void kernel_launch(void* const* d_in, const int* in_sizes, int n_in,
                              void* d_out, int out_size, void* d_ws, size_t ws_size,
                              hipStream_t stream) {
    const float* z   = (const float*)d_in[0];
    const int*   eli = (const int*)d_in[1];      // int64 in reference -> int32 on device
    const float* W1  = (const float*)d_in[2];
    const float* b1  = (const float*)d_in[3];
    const float* W2  = (const float*)d_in[4];
    const float* b2  = (const float*)d_in[5];
    float*       out = (float*)d_out;

    const int E      = in_sizes[1] / 2;
    const int nnodes = in_sizes[0] / 256;

    const size_t ZB  = (size_t)nnodes * 256 * 2;   // z in bf16
    const size_t BTB = (size_t)512 * 128 * 2;      // W1^T in bf16

    const int grid_main = (E + 255) / 256;

    if (ws_size >= ZB + BTB) {
        unsigned short* zb = (unsigned short*)d_ws;
        unsigned short* BT = (unsigned short*)((char*)d_ws + ZB);
        int n4 = nnodes * 64;
        cvt_z<<<(n4 + 255) / 256, 256, 0, stream>>>(z, zb, n4);
        cvt_w1<<<256, 256, 0, stream>>>(W1, BT);
        fused_mlp<true><<<grid_main, 256, 0, stream>>>(nullptr, zb, eli, E, nnodes, BT, b1, W2, b2, out);
    } else if (ws_size >= BTB) {
        unsigned short* BT = (unsigned short*)d_ws;
        cvt_w1<<<256, 256, 0, stream>>>(W1, BT);
        fused_mlp<false><<<grid_main, 256, 0, stream>>>(z, nullptr, eli, E, nnodes, BT, b1, W2, b2, out);
    } else {
        naive_edge<<<E, 128, 0, stream>>>(z, eli, E, nnodes, W1, b1, W2, b2, out);
    }
}